// Round 8
// baseline (47.079 us; speedup 1.0000x reference)
//
#include <hip/hip_runtime.h>
#include <hip/hip_bf16.h>
#include <stdint.h>

#define BATCH 8
#define TSEQ 2048
#define DM 1024
#define NQKV 192

typedef short bf16x8 __attribute__((ext_vector_type(8)));
typedef short short4v __attribute__((ext_vector_type(4)));
typedef float f32x4 __attribute__((ext_vector_type(4)));

static __device__ __forceinline__ short f2bf(float f) {
    union { float f; uint32_t u; } v; v.f = f;
    uint32_t u = v.u;
    uint32_t r = (u + 0x7FFFu + ((u >> 16) & 1u)) >> 16;
    return (short)r;
}

static __device__ __forceinline__ f32x4 mfma16(bf16x8 a, bf16x8 b, f32x4 c) {
    return __builtin_amdgcn_mfma_f32_16x16x32_bf16(a, b, c, 0, 0, 0);
}

// lgkm-only barrier: does NOT drain outstanding global (vmcnt) loads.
static __device__ __forceinline__ void lds_barrier() {
    asm volatile("s_waitcnt lgkmcnt(0)" ::: "memory");
    __builtin_amdgcn_s_barrier();
    asm volatile("" ::: "memory");
}

// Kernel 0: wt2[kchunk=0..127][n=0..191][8]. grid 128 x 192 threads.
__global__ __launch_bounds__(192) void prep_wt(const float* __restrict__ Wq,
                                               const float* __restrict__ Wk,
                                               const float* __restrict__ Wv,
                                               short* __restrict__ wt2) {
    int kc = blockIdx.x;
    int n = threadIdx.x;
    const float* src = (n < 64) ? Wq : (n < 128) ? Wk : Wv;
    int nn = n & 63;
    bf16x8 v;
    #pragma unroll
    for (int e = 0; e < 8; ++e)
        v[e] = f2bf(src[(kc * 8 + e) * 64 + nn]);
    *(bf16x8*)(wt2 + ((size_t)kc * 192 + n) * 8) = v;
}

// Kernel 1: QKV GEMM. grid 512 x 256 (4 waves), 2 blocks/CU.
// Identical to R7 except: main-loop barriers are lgkm-only (no vmcnt drain),
// so global register prefetches stay in flight across barriers.
__global__ __launch_bounds__(256, 2) void qkv_gemm(const float* __restrict__ x,
                                                   const short* __restrict__ wt2,
                                                   short* __restrict__ qo,
                                                   short* __restrict__ kq,
                                                   short* __restrict__ vq) {
    __shared__ short Ab[2][32 * 32];   // 2 x 2 KB bf16
    __shared__ short Cs[32][192];      // 12 KB epilogue staging
    int tid = threadIdx.x;
    int l = tid & 63, w = tid >> 6;
    int col = l & 15, g = l >> 4;
    int row0 = blockIdx.x * 32;

    int arow = tid >> 3, ap = tid & 7;
    const float* gA = x + (size_t)(row0 + arow) * DM + ap * 4;
    // write slot: granule (ap>>1)^((arow>>1)&3), half ap&1
    int awdst = arow * 32 + (((ap >> 1) ^ ((arow >> 1) & 3)) * 8) + (ap & 1) * 4;

    f32x4 acc[2][3];
    #pragma unroll
    for (int mf = 0; mf < 2; ++mf)
        #pragma unroll
        for (int nf = 0; nf < 3; ++nf) acc[mf][nf] = (f32x4){0.f, 0.f, 0.f, 0.f};

    // prologue
    float4 r0 = *(const float4*)(gA);
    float4 rcur = *(const float4*)(gA + 32);
    {
        short4v s = {f2bf(r0.x), f2bf(r0.y), f2bf(r0.z), f2bf(r0.w)};
        *(short4v*)&Ab[0][awdst] = s;
    }
    const short* bpw = wt2 + ((size_t)g * 192 + w * 48 + col) * 8;
    bf16x8 bcur[3], bnxt[3];
    #pragma unroll
    for (int nf = 0; nf < 3; ++nf)
        bcur[nf] = *(const bf16x8*)(bpw + (size_t)nf * 16 * 8);
    lds_barrier();

    // frag read offsets (granule g ^ ((r>>1)&3))
    int afr0, afr1;
    {
        int r0_ = col, r1_ = 16 + col;
        afr0 = r0_ * 32 + ((g ^ ((r0_ >> 1) & 3)) * 8);
        afr1 = r1_ * 32 + ((g ^ ((r1_ >> 1) & 3)) * 8);
    }

    for (int t = 0; t < 32; ++t) {
        float4 rn;
        if (t + 2 < 32) rn = *(const float4*)(gA + (t + 2) * 32);
        if (t + 1 < 32) {
            #pragma unroll
            for (int nf = 0; nf < 3; ++nf)
                bnxt[nf] = *(const bf16x8*)(bpw + ((size_t)(t + 1) * 4 * 192 + nf * 16) * 8);
            short4v s = {f2bf(rcur.x), f2bf(rcur.y), f2bf(rcur.z), f2bf(rcur.w)};
            *(short4v*)&Ab[(t + 1) & 1][awdst] = s;
        }
        bf16x8 a0 = *(const bf16x8*)&Ab[t & 1][afr0];
        bf16x8 a1 = *(const bf16x8*)&Ab[t & 1][afr1];
        #pragma unroll
        for (int nf = 0; nf < 3; ++nf) {
            acc[0][nf] = mfma16(a0, bcur[nf], acc[0][nf]);
            acc[1][nf] = mfma16(a1, bcur[nf], acc[1][nf]);
        }
        lds_barrier();
        rcur = rn;
        #pragma unroll
        for (int nf = 0; nf < 3; ++nf) bcur[nf] = bnxt[nf];
    }

    // epilogue: dump (C/D layout col=lane&15, row=g*4+j) to Cs, then wide stores
    #pragma unroll
    for (int mf = 0; mf < 2; ++mf)
        #pragma unroll
        for (int nf = 0; nf < 3; ++nf) {
            int c = w * 48 + nf * 16 + col;
            #pragma unroll
            for (int j = 0; j < 4; ++j) {
                float sv = acc[mf][nf][j];
                if (c < 64) sv *= 0.03125f;
                Cs[mf * 16 + g * 4 + j][c] = f2bf(sv);
            }
        }
    __syncthreads();
    int b_ = row0 >> 11;
    int t0 = row0 & 2047;
    {   // q: [b][t][64] row-major (pre-scaled)
        int r = tid >> 3, c0 = (tid & 7) * 8;
        bf16x8 vv = *(const bf16x8*)&Cs[r][c0];
        *(bf16x8*)(qo + ((size_t)(b_ * TSEQ + t0 + r)) * 64 + c0) = vv;
    }
    {   // k: kq[b][chunk=d>>3][t][8]
        int chunk = tid >> 5, tl = tid & 31;
        bf16x8 vv = *(const bf16x8*)&Cs[tl][64 + chunk * 8];
        *(bf16x8*)(kq + ((size_t)(b_ * 8 + chunk) * TSEQ + t0 + tl) * 8) = vv;
    }
    {   // v: vq[b][kchunk=t>>3][d][8]
        int tc = tid >> 6, d = tid & 63;
        bf16x8 vv;
        #pragma unroll
        for (int e = 0; e < 8; ++e) vv[e] = Cs[tc * 8 + e][128 + d];
        *(bf16x8*)(vq + (((size_t)b_ * 256 + (t0 >> 3) + tc) * 64 + d) * 8) = vv;
    }
}

// Kernel 2: causal flash attention. grid 384 x 256 (4 independent waves).
// (unchanged from R6/R7)
__global__ __launch_bounds__(256) void attn(const short* __restrict__ qm,
                                            const short* __restrict__ kq,
                                            const short* __restrict__ vq,
                                            float* __restrict__ out) {
    __shared__ short Pb[4][16 * 64];
    __shared__ float Om[2][16][64];
    __shared__ float Ps[2][16];
    int tid = threadIdx.x;
    int l = tid & 63, w = tid >> 6;
    int col = l & 15, g = l >> 4;

    int Bk = blockIdx.x;
    int bb = Bk & 7;
    int jj = Bk >> 3;
    bool high = (jj < 32);
    int qt, kt0, kt1;
    if (high) {
        int hp = 62 - 2 * jj + (w >> 1);
        qt = 64 + hp;
        int nt = (qt >> 2) + 1;
        int nh = nt >> 1;
        kt0 = (w & 1) ? nh : 0;
        kt1 = (w & 1) ? nt : nh;
    } else {
        int i = 47 - jj;
        qt = 4 * i + w;
        kt0 = 0;
        kt1 = (qt >> 2) + 1;
    }
    int q0 = qt * 16;
    int lastkt = qt >> 2;

    const short* qrow = qm + (size_t)(bb * TSEQ + q0 + col) * 64 + g * 8;
    bf16x8 qa0 = *(const bf16x8*)(qrow);
    bf16x8 qa1 = *(const bf16x8*)(qrow + 32);

    const short* kb_ = kq + (size_t)(bb * 8 + g) * TSEQ * 8;
    const short* kb4 = kq + (size_t)(bb * 8 + 4 + g) * TSEQ * 8;
    const short* vb_ = vq + ((size_t)bb * 256 + g) * 64 * 8;

    float psum[4] = {0.f, 0.f, 0.f, 0.f};
    f32x4 o[4];
    #pragma unroll
    for (int df = 0; df < 4; ++df) o[df] = (f32x4){0.f, 0.f, 0.f, 0.f};

    short* Pw = &Pb[w][0];

    bf16x8 kcur[8], knxt[8];
    {
        int key0 = kt0 * 64 + col;
        #pragma unroll
        for (int kf = 0; kf < 4; ++kf) {
            kcur[kf * 2]     = *(const bf16x8*)(kb_ + (size_t)(key0 + kf * 16) * 8);
            kcur[kf * 2 + 1] = *(const bf16x8*)(kb4 + (size_t)(key0 + kf * 16) * 8);
        }
    }

    for (int kt = kt0; kt < kt1; ++kt) {
        int k0 = kt * 64;
        f32x4 s[4];
        #pragma unroll
        for (int kf = 0; kf < 4; ++kf) {
            f32x4 a = (f32x4){0.f, 0.f, 0.f, 0.f};
            a = mfma16(qa0, kcur[kf * 2], a);
            a = mfma16(qa1, kcur[kf * 2 + 1], a);
            s[kf] = a;
        }
        bf16x8 vfr[8];
        const short* vt0 = vb_ + (size_t)(k0 >> 3) * 64 * 8;
        #pragma unroll
        for (int df = 0; df < 4; ++df) {
            int d = df * 16 + col;
            vfr[df * 2]     = *(const bf16x8*)(vt0 + (size_t)d * 8);
            vfr[df * 2 + 1] = *(const bf16x8*)(vt0 + (size_t)(256 + d) * 8);
        }
        if (kt + 1 < kt1) {
            int key0 = (kt + 1) * 64 + col;
            #pragma unroll
            for (int kf = 0; kf < 4; ++kf) {
                knxt[kf * 2]     = *(const bf16x8*)(kb_ + (size_t)(key0 + kf * 16) * 8);
                knxt[kf * 2 + 1] = *(const bf16x8*)(kb4 + (size_t)(key0 + kf * 16) * 8);
            }
        }
        if (kt == lastkt) {
            #pragma unroll
            for (int kf = 0; kf < 4; ++kf) {
                int key = k0 + kf * 16 + col;
                #pragma unroll
                for (int j = 0; j < 4; ++j)
                    if (key > q0 + g * 4 + j) s[kf][j] = -1e30f;
            }
        }
        #pragma unroll
        for (int kf = 0; kf < 4; ++kf)
            #pragma unroll
            for (int j = 0; j < 4; ++j) {
                float pv = __expf(s[kf][j]);
                psum[j] += pv;
                int rr = g * 4 + j;
                int c = kf * 16 + col;
                Pw[rr * 64 + ((((c >> 3) ^ (rr & 7)) << 3) | (c & 7))] = f2bf(pv);
            }
        bf16x8 pa0 = *(const bf16x8*)(Pw + col * 64 + ((g ^ (col & 7)) << 3));
        bf16x8 pa1 = *(const bf16x8*)(Pw + col * 64 + (((4 + g) ^ (col & 7)) << 3));
        #pragma unroll
        for (int df = 0; df < 4; ++df) {
            o[df] = mfma16(pa0, vfr[df * 2], o[df]);
            o[df] = mfma16(pa1, vfr[df * 2 + 1], o[df]);
        }
        #pragma unroll
        for (int i2 = 0; i2 < 8; ++i2) kcur[i2] = knxt[i2];
    }

    #pragma unroll
    for (int off = 1; off <= 8; off <<= 1)
        #pragma unroll
        for (int j = 0; j < 4; ++j)
            psum[j] += __shfl_xor(psum[j], off);

    if (high) {
        int pr = w >> 1;
        if (w & 1) {
            #pragma unroll
            for (int df = 0; df < 4; ++df)
                #pragma unroll
                for (int j = 0; j < 4; ++j)
                    Om[pr][g * 4 + j][df * 16 + col] = o[df][j];
            if (col == 0)
                #pragma unroll
                for (int j = 0; j < 4; ++j) Ps[pr][g * 4 + j] = psum[j];
        }
        __syncthreads();
        if (!(w & 1)) {
            float inv[4];
            #pragma unroll
            for (int j = 0; j < 4; ++j) inv[j] = 1.f / (psum[j] + Ps[pr][g * 4 + j]);
            #pragma unroll
            for (int df = 0; df < 4; ++df)
                #pragma unroll
                for (int j = 0; j < 4; ++j) {
                    float vv = (o[df][j] + Om[pr][g * 4 + j][df * 16 + col]) * inv[j];
                    out[(size_t)(bb * TSEQ + q0 + g * 4 + j) * 64 + df * 16 + col] = vv;
                }
        }
    } else {
        #pragma unroll
        for (int df = 0; df < 4; ++df)
            #pragma unroll
            for (int j = 0; j < 4; ++j)
                out[(size_t)(bb * TSEQ + q0 + g * 4 + j) * 64 + df * 16 + col] = o[df][j] / psum[j];
    }
}

extern "C" void kernel_launch(void* const* d_in, const int* in_sizes, int n_in,
                              void* d_out, int out_size, void* d_ws, size_t ws_size,
                              hipStream_t stream) {
    const float* x  = (const float*)d_in[0];
    const float* Wq = (const float*)d_in[1];
    const float* Wk = (const float*)d_in[2];
    const float* Wv = (const float*)d_in[3];
    float* out = (float*)d_out;

    char* ws = (char*)d_ws;
    short* wt2 = (short*)(ws);                        // 384 KB
    short* qb  = (short*)(ws + 0x60000);              // 2 MB
    short* kqb = (short*)(ws + 0x60000 + 0x200000);   // 2 MB
    short* vqb = (short*)(ws + 0x60000 + 0x400000);   // 2 MB

    prep_wt<<<128, 192, 0, stream>>>(Wq, Wk, Wv, wt2);
    qkv_gemm<<<512, 256, 0, stream>>>(x, wt2, qb, kqb, vqb);
    attn<<<384, 256, 0, stream>>>(qb, kqb, vqb, out);
}